// Round 9
// baseline (756.700 us; speedup 1.0000x reference)
//
#include <hip/hip_runtime.h>

#define H 512
#define TSTEPS 196
#define FLEN 784
#define NBATCH 256

typedef float f4 __attribute__((ext_vector_type(4)));
typedef unsigned long long ull;

// ws layout: 4 weight slots of 513 columns (512 transposed cols + 1 zero pad
// column), then mask bitmaps.
//   slot s (bytes): [s*1050624, +1050624)   column k at s*1050624 + k*2048
//   pad column byte offset within slot = 512<<11 = 1048576
//   bitmaps (floats offset MBOFF_F): mb1[196*8] ull, mb2, mb3
#define SLOTB  1050624u            // bytes per slot (513*512*4)
#define SLOTF  262656              // floats per slot
#define PADOFF 1048576u            // byte offset of zero column within slot
#define MBOFF_F 1050624            // float offset of bitmaps (= 4 slots)

__global__ void transpose4(const float* __restrict__ a,
                           const float* __restrict__ b,
                           const float* __restrict__ c,
                           const float* __restrict__ d,
                           float* __restrict__ ws)
{
    __shared__ float tile[32][33];
    const float* src = (blockIdx.z == 0) ? a : (blockIdx.z == 1) ? b
                     : (blockIdx.z == 2) ? c : d;
    float* dst = ws + (size_t)blockIdx.z * SLOTF;
    int bx = blockIdx.x * 32, by = blockIdx.y * 32;
    int tx = threadIdx.x, ty = threadIdx.y;
    for (int r = ty; r < 32; r += 8)
        tile[r][tx] = src[(by + r) * H + bx + tx];
    __syncthreads();
    for (int r = ty; r < 32; r += 8)
        dst[(bx + r) * H + by + tx] = tile[tx][r];
}

// z<3: pack masks into bitmaps (mb[z][t*8+w] bit l = mask[64w+l, t] != 0)
// z==3: zero the 4 pad columns
__global__ void maskbits(const float* __restrict__ m1, const float* __restrict__ m2,
                         const float* __restrict__ m3, float* __restrict__ ws)
{
    int t = blockIdx.x;          // 0..195
    int z = blockIdx.y;          // 0..3
    int l = threadIdx.x;         // 0..63
    if (z == 3) {
        int idx = t * 64 + l;
        if (idx < 4 * 512) {
            int slot = idx >> 9, pos = idx & 511;
            ws[(size_t)slot * SLOTF + 512 * 512 + pos] = 0.0f;
        }
        return;
    }
    ull* mb = (ull*)(ws + MBOFF_F);
    const float* src = (z == 0) ? m1 : (z == 1) ? m2 : m3;
    for (int w = 0; w < 8; ++w) {
        ull bl = __ballot(src[(w * 64 + l) * FLEN + t] != 0.0f);
        if (l == 0) mb[(size_t)z * (TSTEPS * 8) + t * 8 + w] = bl;
    }
}

// Flat gather: sum this thread's 16B slice of columns list[lo..hi).
// lo,hi multiples of 4 (lists zero-column padded) -> no tail code at all.
__device__ __forceinline__ f4 gsingle(const char* __restrict__ base,
                                      const unsigned* __restrict__ list,
                                      int lo, int hi, unsigned uoff)
{
    f4 a0 = (f4)0.0f, a1 = (f4)0.0f, a2 = (f4)0.0f, a3 = (f4)0.0f;
    for (int i = lo; i < hi; i += 4) {
        unsigned o0 = list[i]     + uoff;
        unsigned o1 = list[i + 1] + uoff;
        unsigned o2 = list[i + 2] + uoff;
        unsigned o3 = list[i + 3] + uoff;
        a0 += *(const f4*)(base + o0);
        a1 += *(const f4*)(base + o1);
        a2 += *(const f4*)(base + o2);
        a3 += *(const f4*)(base + o3);
    }
    return (a0 + a1) + (a2 + a3);
}

__device__ __forceinline__ float sum8(const float* __restrict__ p, int j)
{
    float s0 = p[j] + p[512 + j];
    float s1 = p[1024 + j] + p[1536 + j];
    float s2 = p[2048 + j] + p[2560 + j];
    float s3 = p[3072 + j] + p[3584 + j];
    return (s0 + s1) + (s2 + s3);
}

__device__ __forceinline__ float mbit(const ull* __restrict__ mb, int t, int j)
{
    return ((mb[t * 8 + (j >> 6)] >> (j & 63)) & 1ull) ? 1.0f : 0.0f;
}

// lag pipeline, per iteration t = 0..TSTEPS+1:
//   P0: ONE gather phase @ lists from t-1, each walk PREDICATED by the
//       consuming step's mask nibble (dead output rows are never fetched):
//       pU1 = Wh1@L1        [consumer U1(t),   mask mb1(t)]
//       pU2 = Wi2@L1+Wh2@L2 [consumer U2(t-1), mask mb2(t-1)]
//       pU3 = Wi3@L2        [consumer U3(t-2), mask mb3(t-2)]
//   P1: lower half U1(t); upper half U2(t-1), U3(t-2); ballots -> lists
__global__ __launch_bounds__(1024)
void lsnn_main(const float* __restrict__ x,
               const float* __restrict__ Wi1,
               const float* __restrict__ bi1, const float* __restrict__ bh1,
               const float* __restrict__ bi2, const float* __restrict__ bh2,
               const float* __restrict__ bi3,
               const float* __restrict__ Wo,  const float* __restrict__ bo,
               const float* __restrict__ tau1, const float* __restrict__ tau2,
               const float* __restrict__ tau3,
               const float* __restrict__ ws,
               float* __restrict__ out)
{
    const char* wsb  = (const char*)ws;
    const char* B_H1 = wsb;
    const char* B_I2 = wsb + SLOTB;
    const char* B_H2 = wsb + 2 * SLOTB;
    const char* B_I3 = wsb + 3 * SLOTB;
    const ull* mb1 = (const ull*)(ws + MBOFF_F);
    const ull* mb2 = mb1 + TSTEPS * 8;
    const ull* mb3 = mb2 + TSTEPS * 8;

    const int n    = blockIdx.x;
    const int tid  = threadIdx.x;
    const int lane = tid & 63;
    const bool lowh = tid < 512;
    const int j    = lowh ? tid : tid - 512;   // neuron index within half
    const int w8   = (tid >> 6) & 7;           // wave id within half
    const int u    = tid & 127;                // 16B slice id (rows 4u..4u+3)
    const int g    = tid >> 7;                 // gather group 0..7
    const unsigned uoff = (unsigned)u << 4;

    __shared__ f4       pU1[8][128], pU2[8][128], pU3[8][128];
    __shared__ unsigned L1[H], L2[H];
    __shared__ ull      ballS[16];   // [0..7]=ball(s1), [8..15]=ball(s2)

    // per-half parameter/state registers
    float4 wi; float bs1, ro1, omr1, mem1, b1, s1;           // lower
    float bs2, ro2, omr2, mem2, b2, s2;                      // upper
    float bs3, ro3, omr3, mem3, b3, s3, cnt3;                // upper
    const float alpha = expf(-1.0f / 20.0f);
    const float oma = 1.0f - alpha;
    if (lowh) {
        wi  = reinterpret_cast<const float4*>(Wi1)[j];
        bs1 = bi1[j] + bh1[j];
        ro1 = expf(-1.0f / tau1[j]); omr1 = 1.0f - ro1;
        mem1 = 0.f; b1 = 0.01f; s1 = 0.f;
    } else {
        bs2 = bi2[j] + bh2[j];
        bs3 = bi3[j];
        ro2 = expf(-1.0f / tau2[j]); omr2 = 1.0f - ro2;
        ro3 = expf(-1.0f / tau3[j]); omr3 = 1.0f - ro3;
        mem2 = 0.f; b2 = 0.01f; s2 = 0.f;
        mem3 = 0.f; b3 = 0.01f; s3 = 0.f; cnt3 = 0.f;
    }

    int na1 = 0, na2 = 0, na1p = 0, na2p = 0;
    const float* xr = x + n * FLEN;

    if (tid < 16) ballS[tid] = 0ull;
    __syncthreads();

    for (int t = 0; t <= TSTEPS + 1; ++t) {
        // ---------------- P0: predicated merged gather ----------------
        {
            // liveness nibbles (rows 4u..4u+3) for each consumer step
            unsigned nib1 = 0, nib2 = 0, nib3 = 0;
            if (t < TSTEPS)
                nib1 = (unsigned)((mb1[t * 8 + (u >> 4)] >> ((u & 15) * 4)) & 0xFull);
            if (t >= 1 && t - 1 < TSTEPS)
                nib2 = (unsigned)((mb2[(t - 1) * 8 + (u >> 4)] >> ((u & 15) * 4)) & 0xFull);
            if (t >= 2)
                nib3 = (unsigned)((mb3[(t - 2) * 8 + (u >> 4)] >> ((u & 15) * 4)) & 0xFull);

            int lo1 = ((na1p * g) >> 3) & ~3, hi1 = ((na1p * (g + 1)) >> 3) & ~3;
            int lo2 = ((na2p * g) >> 3) & ~3, hi2 = ((na2p * (g + 1)) >> 3) & ~3;

            f4 aU1 = (f4)0.0f, aU2 = (f4)0.0f, aU3 = (f4)0.0f;
            if (nib1) aU1 = gsingle(B_H1, L1, lo1, hi1, uoff);
            if (nib2) {
                aU2 = gsingle(B_I2, L1, lo1, hi1, uoff);
                aU2 += gsingle(B_H2, L2, lo2, hi2, uoff);
            }
            if (nib3) aU3 = gsingle(B_I3, L2, lo2, hi2, uoff);
            pU1[g][u] = aU1;
            pU2[g][u] = aU2;
            pU3[g][u] = aU3;
        }
        __syncthreads();                           // B1

        // ---------------- P1: updates (both halves busy) ----------------
        if (lowh) {
            ull ball = 0;
            if (t < TSTEPS) {
                float mk1 = mbit(mb1, t, j);
                int base = (t < 48) ? (4 * t) : (FLEN - 4);
                float4 xv = *reinterpret_cast<const float4*>(xr + base);
                float h1 = wi.x * xv.x + wi.y * xv.y + wi.z * xv.z + wi.w * xv.w
                         + bs1 + sum8((const float*)&pU1[0][0], j);
                b1 = ro1 * b1 + omr1 * s1;
                float Bth = 0.01f + 1.8f * b1;
                float nm = mem1 * alpha + oma * h1 - Bth * s1;
                mem1 = (mk1 == 0.0f) ? mem1 : nm;
                s1 = (mem1 - Bth > 0.0f) ? mk1 : 0.0f;
                ball = __ballot(s1 != 0.0f);
            }
            if (lane == 0) ballS[w8] = ball;
        } else {
            ull ball = 0;
            int t2 = t - 1;
            if (t2 >= 0 && t2 < TSTEPS) {
                float mk2 = mbit(mb2, t2, j);
                float h2 = bs2 + sum8((const float*)&pU2[0][0], j);
                b2 = ro2 * b2 + omr2 * s2;
                float Bth = 0.01f + 1.8f * b2;
                float nm = mem2 * alpha + oma * h2 - Bth * s2;
                mem2 = (mk2 == 0.0f) ? mem2 : nm;
                s2 = (mem2 - Bth > 0.0f) ? mk2 : 0.0f;
                ball = __ballot(s2 != 0.0f);
            }
            if (lane == 0) ballS[8 + w8] = ball;
            int t3 = t - 2;
            if (t3 >= 0 && t3 < TSTEPS) {
                float mk3 = mbit(mb3, t3, j);
                float h3 = bs3 + sum8((const float*)&pU3[0][0], j);
                b3 = ro3 * b3 + omr3 * s3;
                float Bth = 0.01f + 1.8f * b3;
                float nm = mem3 * alpha + oma * h3 - Bth * s3;
                mem3 = (mk3 == 0.0f) ? mem3 : nm;
                s3 = (mem3 - Bth > 0.0f) ? mk3 : 0.0f;
                cnt3 += s3;                        // deferred output GEMV
            }
        }
        __syncthreads();                           // B2

        // ---------------- build padded lists from ballots ----------------
        {
            ull bw[16];
            int c[16];
#pragma unroll
            for (int w = 0; w < 16; ++w) { bw[w] = ballS[w]; c[w] = __popcll(bw[w]); }
            int t1 = 0, t2s = 0;
#pragma unroll
            for (int w = 0; w < 8; ++w) { t1 += c[w]; t2s += c[8 + w]; }
            if (lowh) {
                int pos = 0;
#pragma unroll
                for (int w = 0; w < 8; ++w) if (w < w8) pos += c[w];
                pos += __popcll(bw[w8] & ((1ull << lane) - 1ull));
                if ((bw[w8] >> lane) & 1ull) L1[pos] = (unsigned)j << 11;
            } else {
                int pos = 0;
#pragma unroll
                for (int w = 0; w < 8; ++w) if (w < w8) pos += c[8 + w];
                pos += __popcll(bw[8 + w8] & ((1ull << lane) - 1ull));
                if ((bw[8 + w8] >> lane) & 1ull) L2[pos] = (unsigned)j << 11;
            }
            na1 = t1; na2 = t2s;
            na1p = (na1 + 3) & ~3; na2p = (na2 + 3) & ~3;
            if (tid < 4)      { if (na1 + tid < na1p) L1[na1 + tid] = PADOFF; }
            else if (tid < 8) { int q = tid - 4; if (na2 + q < na2p) L2[na2 + q] = PADOFF; }
        }
        __syncthreads();                           // B3
    }

    // ---- output: out[n,o] = (Wo[o,:]·cnt3 + T*bo[o]) / T ----
    float* c3 = (float*)&pU1[0][0];
    if (!lowh) c3[j] = cnt3;
    __syncthreads();
    int wv = tid >> 6;   // 0..15
    for (int o = wv; o < 10; o += 16) {
        float p = 0.0f;
        for (int i = lane; i < H; i += 64)
            p += Wo[o * H + i] * c3[i];
        for (int off = 32; off > 0; off >>= 1)
            p += __shfl_down(p, off);
        if (lane == 0)
            out[n * 10 + o] = (p + 196.0f * bo[o]) / 196.0f;
    }
}

extern "C" void kernel_launch(void* const* d_in, const int* in_sizes, int n_in,
                              void* d_out, int out_size, void* d_ws, size_t ws_size,
                              hipStream_t stream)
{
    const float* x    = (const float*)d_in[0];
    const float* Wi1  = (const float*)d_in[1];
    const float* bi1  = (const float*)d_in[2];
    const float* Wh1  = (const float*)d_in[3];
    const float* bh1  = (const float*)d_in[4];
    const float* Wi2  = (const float*)d_in[5];
    const float* bi2  = (const float*)d_in[6];
    const float* Wh2  = (const float*)d_in[7];
    const float* bh2  = (const float*)d_in[8];
    const float* Wi3  = (const float*)d_in[9];
    const float* bi3  = (const float*)d_in[10];
    const float* Wo   = (const float*)d_in[11];
    const float* bo   = (const float*)d_in[12];
    const float* tau1 = (const float*)d_in[13];
    const float* tau2 = (const float*)d_in[14];
    const float* tau3 = (const float*)d_in[15];
    const float* m1   = (const float*)d_in[16];
    const float* m2   = (const float*)d_in[17];
    const float* m3   = (const float*)d_in[18];

    float* ws  = (float*)d_ws;
    float* out = (float*)d_out;

    // pre-pass: transpose Wh1,Wi2,Wh2,Wi3 into 513-col slots; bitmaps + pads
    transpose4<<<dim3(16, 16, 4), dim3(32, 8, 1), 0, stream>>>(Wh1, Wi2, Wh2, Wi3, ws);
    maskbits<<<dim3(TSTEPS, 4, 1), 64, 0, stream>>>(m1, m2, m3, ws);

    // main persistent kernel: 1 sample per workgroup (256 WGs, 1024 thr, 16 waves)
    lsnn_main<<<NBATCH, 1024, 0, stream>>>(x, Wi1, bi1, bh1, bi2, bh2, bi3,
                                           Wo, bo, tau1, tau2, tau3, ws, out);
}

// Round 10
// 694.780 us; speedup vs baseline: 1.0891x; 1.0891x over previous
//
#include <hip/hip_runtime.h>

#define H 512
#define TSTEPS 196
#define FLEN 784
#define NBATCH 256

typedef float f4 __attribute__((ext_vector_type(4)));
typedef unsigned long long ull;

// ws layout: 4 weight slots of 513 columns (512 transposed cols + 1 zero pad
// column used by list padding), then mask bitmaps.
//   slot s bytes [s*1050624, +1050624); column k at s*1050624 + k*2048
//   bitmaps (float offset MBOFF_F): mb1[196*8] ull, mb2, mb3
#define SLOTB  1050624u            // bytes per slot (513*512*4)
#define SLOTF  262656              // floats per slot
#define PADOFF 1048576u            // byte offset of zero column within slot
#define MBOFF_F 1050624            // float offset of bitmaps (= 4 slots)

__global__ void transpose4(const float* __restrict__ a,
                           const float* __restrict__ b,
                           const float* __restrict__ c,
                           const float* __restrict__ d,
                           float* __restrict__ ws)
{
    __shared__ float tile[32][33];
    const float* src = (blockIdx.z == 0) ? a : (blockIdx.z == 1) ? b
                     : (blockIdx.z == 2) ? c : d;
    float* dst = ws + (size_t)blockIdx.z * SLOTF;
    int bx = blockIdx.x * 32, by = blockIdx.y * 32;
    int tx = threadIdx.x, ty = threadIdx.y;
    for (int r = ty; r < 32; r += 8)
        tile[r][tx] = src[(by + r) * H + bx + tx];
    __syncthreads();
    for (int r = ty; r < 32; r += 8)
        dst[(bx + r) * H + by + tx] = tile[tx][r];
}

// z<3: pack masks into bitmaps (mb[z][t*8+w] bit l = mask[64w+l, t] != 0)
// z==3: zero the 4 pad columns
__global__ void maskbits(const float* __restrict__ m1, const float* __restrict__ m2,
                         const float* __restrict__ m3, float* __restrict__ ws)
{
    int t = blockIdx.x;          // 0..195
    int z = blockIdx.y;          // 0..3
    int l = threadIdx.x;         // 0..63
    if (z == 3) {
        int idx = t * 64 + l;
        if (idx < 4 * 512) {
            int slot = idx >> 9, pos = idx & 511;
            ws[(size_t)slot * SLOTF + 512 * 512 + pos] = 0.0f;
        }
        return;
    }
    ull* mb = (ull*)(ws + MBOFF_F);
    const float* src = (z == 0) ? m1 : (z == 1) ? m2 : m3;
    for (int w = 0; w < 8; ++w) {
        ull bl = __ballot(src[(w * 64 + l) * FLEN + t] != 0.0f);
        if (l == 0) mb[(size_t)z * (TSTEPS * 8) + t * 8 + w] = bl;
    }
}

// Pair gather over list[lo,hi) (lo,hi multiples of 8; entries are byte column
// offsets incl. zero-pad columns). One ds_read_b128 per 4 entries; 16 loads
// in flight per iteration; no tail code.
__device__ __forceinline__ void gpair8(const char* __restrict__ bA,
                                       const char* __restrict__ bB,
                                       const int* __restrict__ list,
                                       int lo, int hi, unsigned uoff,
                                       f4& accA, f4& accB)
{
    for (int i = lo; i < hi; i += 8) {
        int4 la = *(const int4*)(list + i);
        int4 lb = *(const int4*)(list + i + 4);
        unsigned o0 = (unsigned)la.x + uoff, o1 = (unsigned)la.y + uoff;
        unsigned o2 = (unsigned)la.z + uoff, o3 = (unsigned)la.w + uoff;
        unsigned o4 = (unsigned)lb.x + uoff, o5 = (unsigned)lb.y + uoff;
        unsigned o6 = (unsigned)lb.z + uoff, o7 = (unsigned)lb.w + uoff;
        f4 va0 = *(const f4*)(bA + o0), vb0 = *(const f4*)(bB + o0);
        f4 va1 = *(const f4*)(bA + o1), vb1 = *(const f4*)(bB + o1);
        f4 va2 = *(const f4*)(bA + o2), vb2 = *(const f4*)(bB + o2);
        f4 va3 = *(const f4*)(bA + o3), vb3 = *(const f4*)(bB + o3);
        f4 va4 = *(const f4*)(bA + o4), vb4 = *(const f4*)(bB + o4);
        f4 va5 = *(const f4*)(bA + o5), vb5 = *(const f4*)(bB + o5);
        f4 va6 = *(const f4*)(bA + o6), vb6 = *(const f4*)(bB + o6);
        f4 va7 = *(const f4*)(bA + o7), vb7 = *(const f4*)(bB + o7);
        accA += ((va0 + va1) + (va2 + va3)) + ((va4 + va5) + (va6 + va7));
        accB += ((vb0 + vb1) + (vb2 + vb3)) + ((vb4 + vb5) + (vb6 + vb7));
    }
}

__device__ __forceinline__ float sum8(const float* __restrict__ p, int j)
{
    float s0 = p[j] + p[512 + j];
    float s1 = p[1024 + j] + p[1536 + j];
    float s2 = p[2048 + j] + p[2560 + j];
    float s3 = p[3072 + j] + p[3584 + j];
    return (s0 + s1) + (s2 + s3);
}

__device__ __forceinline__ float mbit(const ull* __restrict__ mb, int t, int j)
{
    return ((mb[t * 8 + (j >> 6)] >> (j & 63)) & 1ull) ? 1.0f : 0.0f;
}

// lag pipeline, per iteration t = 0..TSTEPS+1:
//   P0: ONE merged gather phase @ lists from t-1 (combined padded index space,
//       [0,na1p) -> L1 walk pairs (Wh1,Wi2), [na1p,tot) -> L2 walk (Wh2,Wi3)):
//       pU1 = Wh1@L1;  pU2 = Wi2@L1 + Wh2@L2;  pU3 = Wi3@L2
//   P1: lower half U1(t); upper half U2(t-1), U3(t-2); ballots
//   P2: build ×8-padded lists from ballots
__global__ __launch_bounds__(1024)
void lsnn_main(const float* __restrict__ x,
               const float* __restrict__ Wi1,
               const float* __restrict__ bi1, const float* __restrict__ bh1,
               const float* __restrict__ bi2, const float* __restrict__ bh2,
               const float* __restrict__ bi3,
               const float* __restrict__ Wo,  const float* __restrict__ bo,
               const float* __restrict__ tau1, const float* __restrict__ tau2,
               const float* __restrict__ tau3,
               const float* __restrict__ ws,
               float* __restrict__ out)
{
    const char* wsb  = (const char*)ws;
    const char* B_H1 = wsb;
    const char* B_I2 = wsb + SLOTB;
    const char* B_H2 = wsb + 2 * SLOTB;
    const char* B_I3 = wsb + 3 * SLOTB;
    const ull* mb1 = (const ull*)(ws + MBOFF_F);
    const ull* mb2 = mb1 + TSTEPS * 8;
    const ull* mb3 = mb2 + TSTEPS * 8;

    const int n    = blockIdx.x;
    const int tid  = threadIdx.x;
    const int lane = tid & 63;
    const bool lowh = tid < 512;
    const int j    = lowh ? tid : tid - 512;   // neuron index within half
    const int w8   = (tid >> 6) & 7;           // wave id within half
    const int u    = tid & 127;                // 16B slice id (rows 4u..4u+3)
    const int g    = tid >> 7;                 // gather group 0..7
    const unsigned uoff = (unsigned)u << 4;

    __shared__ f4 pU1[8][128], pU2[8][128], pU3[8][128];
    __shared__ __align__(16) int L1[H], L2[H];
    __shared__ ull ballS[16];    // [0..7]=ball(s1), [8..15]=ball(s2)

    // per-half parameter/state registers
    float4 wi; float bs1, ro1, omr1, mem1, b1, s1;           // lower
    float bs2, ro2, omr2, mem2, b2, s2;                      // upper
    float bs3, ro3, omr3, mem3, b3, s3, cnt3;                // upper
    const float alpha = expf(-1.0f / 20.0f);
    const float oma = 1.0f - alpha;
    if (lowh) {
        wi  = reinterpret_cast<const float4*>(Wi1)[j];
        bs1 = bi1[j] + bh1[j];
        ro1 = expf(-1.0f / tau1[j]); omr1 = 1.0f - ro1;
        mem1 = 0.f; b1 = 0.01f; s1 = 0.f;
    } else {
        bs2 = bi2[j] + bh2[j];
        bs3 = bi3[j];
        ro2 = expf(-1.0f / tau2[j]); omr2 = 1.0f - ro2;
        ro3 = expf(-1.0f / tau3[j]); omr3 = 1.0f - ro3;
        mem2 = 0.f; b2 = 0.01f; s2 = 0.f;
        mem3 = 0.f; b3 = 0.01f; s3 = 0.f; cnt3 = 0.f;
    }

    int na1 = 0, na2 = 0, na1p = 0, na2p = 0;
    const float* xr = x + n * FLEN;

    if (tid < 16) ballS[tid] = 0ull;
    __syncthreads();

    for (int t = 0; t <= TSTEPS + 1; ++t) {
        // ---------------- P0: merged gather (8-unrolled pair walks) --------
        {
            int tot = na1p + na2p;
            int lo = ((tot * g) >> 3) & ~7, hi = ((tot * (g + 1)) >> 3) & ~7;
            if (g == 7) hi = tot;
            f4 aU1 = (f4)0.0f, aU2 = (f4)0.0f, aU3 = (f4)0.0f;
            int mi = lo < na1p ? (hi < na1p ? hi : na1p) : na1p;
            if (lo < mi)
                gpair8(B_H1, B_I2, L1, lo, mi, uoff, aU1, aU2);
            int lo2 = (lo > na1p ? lo : na1p) - na1p, hi2 = hi - na1p;
            if (lo2 < hi2)
                gpair8(B_H2, B_I3, L2, lo2, hi2, uoff, aU2, aU3);
            pU1[g][u] = aU1;
            pU2[g][u] = aU2;
            pU3[g][u] = aU3;
        }
        __syncthreads();                           // B1

        // ---------------- P1: updates (both halves busy) ----------------
        if (lowh) {
            ull ball = 0;
            if (t < TSTEPS) {
                float mk1 = mbit(mb1, t, j);
                int base = (t < 48) ? (4 * t) : (FLEN - 4);
                float4 xv = *reinterpret_cast<const float4*>(xr + base);
                float h1 = wi.x * xv.x + wi.y * xv.y + wi.z * xv.z + wi.w * xv.w
                         + bs1 + sum8((const float*)&pU1[0][0], j);
                b1 = ro1 * b1 + omr1 * s1;
                float Bth = 0.01f + 1.8f * b1;
                float nm = mem1 * alpha + oma * h1 - Bth * s1;
                mem1 = (mk1 == 0.0f) ? mem1 : nm;
                s1 = (mem1 - Bth > 0.0f) ? mk1 : 0.0f;
                ball = __ballot(s1 != 0.0f);
            }
            if (lane == 0) ballS[w8] = ball;
        } else {
            ull ball = 0;
            int t2 = t - 1;
            if (t2 >= 0 && t2 < TSTEPS) {
                float mk2 = mbit(mb2, t2, j);
                float h2 = bs2 + sum8((const float*)&pU2[0][0], j);
                b2 = ro2 * b2 + omr2 * s2;
                float Bth = 0.01f + 1.8f * b2;
                float nm = mem2 * alpha + oma * h2 - Bth * s2;
                mem2 = (mk2 == 0.0f) ? mem2 : nm;
                s2 = (mem2 - Bth > 0.0f) ? mk2 : 0.0f;
                ball = __ballot(s2 != 0.0f);
            }
            if (lane == 0) ballS[8 + w8] = ball;
            int t3 = t - 2;
            if (t3 >= 0 && t3 < TSTEPS) {
                float mk3 = mbit(mb3, t3, j);
                float h3 = bs3 + sum8((const float*)&pU3[0][0], j);
                b3 = ro3 * b3 + omr3 * s3;
                float Bth = 0.01f + 1.8f * b3;
                float nm = mem3 * alpha + oma * h3 - Bth * s3;
                mem3 = (mk3 == 0.0f) ? mem3 : nm;
                s3 = (mem3 - Bth > 0.0f) ? mk3 : 0.0f;
                cnt3 += s3;                        // deferred output GEMV
            }
        }
        __syncthreads();                           // B2

        // ---------------- P2: build ×8-padded lists from ballots ----------
        {
            ull bw[16];
            int c[16];
#pragma unroll
            for (int w = 0; w < 16; ++w) { bw[w] = ballS[w]; c[w] = __popcll(bw[w]); }
            int t1 = 0, t2s = 0;
#pragma unroll
            for (int w = 0; w < 8; ++w) { t1 += c[w]; t2s += c[8 + w]; }
            if (lowh) {
                int pos = 0;
#pragma unroll
                for (int w = 0; w < 8; ++w) if (w < w8) pos += c[w];
                pos += __popcll(bw[w8] & ((1ull << lane) - 1ull));
                if ((bw[w8] >> lane) & 1ull) L1[pos] = j << 11;
            } else {
                int pos = 0;
#pragma unroll
                for (int w = 0; w < 8; ++w) if (w < w8) pos += c[8 + w];
                pos += __popcll(bw[8 + w8] & ((1ull << lane) - 1ull));
                if ((bw[8 + w8] >> lane) & 1ull) L2[pos] = j << 11;
            }
            na1 = t1; na2 = t2s;
            na1p = (na1 + 7) & ~7; na2p = (na2 + 7) & ~7;
            if (tid < 8)       { if (na1 + tid < na1p) L1[na1 + tid] = (int)PADOFF; }
            else if (tid < 16) { int q = tid - 8; if (na2 + q < na2p) L2[na2 + q] = (int)PADOFF; }
        }
        __syncthreads();                           // B3
    }

    // ---- output: out[n,o] = (Wo[o,:]·cnt3 + T*bo[o]) / T ----
    float* c3 = (float*)&pU1[0][0];
    if (!lowh) c3[j] = cnt3;
    __syncthreads();
    int wv = tid >> 6;   // 0..15
    for (int o = wv; o < 10; o += 16) {
        float p = 0.0f;
        for (int i = lane; i < H; i += 64)
            p += Wo[o * H + i] * c3[i];
        for (int off = 32; off > 0; off >>= 1)
            p += __shfl_down(p, off);
        if (lane == 0)
            out[n * 10 + o] = (p + 196.0f * bo[o]) / 196.0f;
    }
}

extern "C" void kernel_launch(void* const* d_in, const int* in_sizes, int n_in,
                              void* d_out, int out_size, void* d_ws, size_t ws_size,
                              hipStream_t stream)
{
    const float* x    = (const float*)d_in[0];
    const float* Wi1  = (const float*)d_in[1];
    const float* bi1  = (const float*)d_in[2];
    const float* Wh1  = (const float*)d_in[3];
    const float* bh1  = (const float*)d_in[4];
    const float* Wi2  = (const float*)d_in[5];
    const float* bi2  = (const float*)d_in[6];
    const float* Wh2  = (const float*)d_in[7];
    const float* bh2  = (const float*)d_in[8];
    const float* Wi3  = (const float*)d_in[9];
    const float* bi3  = (const float*)d_in[10];
    const float* Wo   = (const float*)d_in[11];
    const float* bo   = (const float*)d_in[12];
    const float* tau1 = (const float*)d_in[13];
    const float* tau2 = (const float*)d_in[14];
    const float* tau3 = (const float*)d_in[15];
    const float* m1   = (const float*)d_in[16];
    const float* m2   = (const float*)d_in[17];
    const float* m3   = (const float*)d_in[18];

    float* ws  = (float*)d_ws;
    float* out = (float*)d_out;

    // pre-pass: transpose Wh1,Wi2,Wh2,Wi3 into 513-col slots; bitmaps + pads
    transpose4<<<dim3(16, 16, 4), dim3(32, 8, 1), 0, stream>>>(Wh1, Wi2, Wh2, Wi3, ws);
    maskbits<<<dim3(TSTEPS, 4, 1), 64, 0, stream>>>(m1, m2, m3, ws);

    // main persistent kernel: 1 sample per workgroup (256 WGs, 1024 thr, 16 waves)
    lsnn_main<<<NBATCH, 1024, 0, stream>>>(x, Wi1, bi1, bh1, bi2, bh2, bi3,
                                           Wo, bo, tau1, tau2, tau3, ws, out);
}

// Round 11
// 668.403 us; speedup vs baseline: 1.1321x; 1.0395x over previous
//
#include <hip/hip_runtime.h>

#define H 512
#define TSTEPS 196
#define FLEN 784
#define NBATCH 256

typedef float f4 __attribute__((ext_vector_type(4)));
typedef unsigned long long ull;

// ws byte layout:
//   [0MB) Wh1^T  [1MB) Wi2^T   <- L1-list pair (partner = +1MB)
//   [2MB) Wh2^T  [3MB) Wi3^T   <- L2-list pair (partner = +1MB)
//   [4MB) 2KB zero column      <- pad target A
//   [5MB) 2KB zero column      <- pad target B
//   [float 1311232) mask bitmaps mb1,mb2,mb3 (each 196*8 ull)
#define PAD1 4194304u   // L1-pair pad coff: 0MB+4MB=zeroA, 1MB+4MB=zeroB
#define PAD2 2097152u   // L2-pair pad coff: 2MB+2MB=zeroA, 3MB+2MB=zeroB
#define ZCOL1_F 1048576
#define ZCOL2_F 1310720
#define MBOFF_F 1311232

__global__ void transpose4(const float* __restrict__ a,
                           const float* __restrict__ b,
                           const float* __restrict__ c,
                           const float* __restrict__ d,
                           float* __restrict__ ws)
{
    __shared__ float tile[32][33];
    const float* src = (blockIdx.z == 0) ? a : (blockIdx.z == 1) ? b
                     : (blockIdx.z == 2) ? c : d;
    float* dst = ws + (size_t)blockIdx.z * (H * H);
    int bx = blockIdx.x * 32, by = blockIdx.y * 32;
    int tx = threadIdx.x, ty = threadIdx.y;
    for (int r = ty; r < 32; r += 8)
        tile[r][tx] = src[(by + r) * H + bx + tx];
    __syncthreads();
    for (int r = ty; r < 32; r += 8)
        dst[(bx + r) * H + by + tx] = tile[tx][r];
}

// z<3: pack masks into bitmaps (mb[z][t*8+w] bit l = mask[64w+l, t] != 0)
// z==3: zero the two 2KB pad columns
__global__ void maskbits(const float* __restrict__ m1, const float* __restrict__ m2,
                         const float* __restrict__ m3, float* __restrict__ ws)
{
    int t = blockIdx.x;          // 0..195
    int z = blockIdx.y;          // 0..3
    int l = threadIdx.x;         // 0..63
    if (z == 3) {
        int idx = t * 64 + l;
        if (idx < 512)            ws[ZCOL1_F + idx] = 0.0f;
        else if (idx < 1024)      ws[ZCOL2_F + idx - 512] = 0.0f;
        return;
    }
    ull* mb = (ull*)(ws + MBOFF_F);
    const float* src = (z == 0) ? m1 : (z == 1) ? m2 : m3;
    for (int w = 0; w < 8; ++w) {
        ull bl = __ballot(src[(w * 64 + l) * FLEN + t] != 0.0f);
        if (l == 0) mb[(size_t)z * (TSTEPS * 8) + t * 8 + w] = bl;
    }
}

// Walk a composite ballot word (bit q <-> neuron j = 64*(q>>3) + 8*pairi + (q&7)),
// summing this thread's 16B slice of the selected columns from BOTH pair
// matrices (bB = bA + 1MB shares coff). Chunk-of-4 predicated extraction:
// exhausted slots load the zero pad column (+0.0f, bit-exact). Extraction is
// uniform (SALU); 8 loads in flight per chunk.
__device__ __forceinline__ void walkpair(const char* __restrict__ bA,
                                         const char* __restrict__ bB,
                                         ull comp, unsigned pairi, unsigned padc,
                                         unsigned uoff, f4& accA, f4& accB)
{
    int cnt = __popcll(comp);
    for (int e = 0; e < cnt; e += 4) {
        unsigned o0, o1, o2, o3;
#define EXT(o) { if (comp) { int q = __builtin_ctzll(comp); comp &= comp - 1ull;  \
                 o = ((((unsigned)q & ~7u) | pairi) << 14) | (((unsigned)q & 7u) << 11); } \
                 else o = padc; }
        EXT(o0) EXT(o1) EXT(o2) EXT(o3)
#undef EXT
        f4 va0 = *(const f4*)(bA + o0 + uoff), vb0 = *(const f4*)(bB + o0 + uoff);
        f4 va1 = *(const f4*)(bA + o1 + uoff), vb1 = *(const f4*)(bB + o1 + uoff);
        f4 va2 = *(const f4*)(bA + o2 + uoff), vb2 = *(const f4*)(bB + o2 + uoff);
        f4 va3 = *(const f4*)(bA + o3 + uoff), vb3 = *(const f4*)(bB + o3 + uoff);
        accA += (va0 + va1) + (va2 + va3);
        accB += (vb0 + vb1) + (vb2 + vb3);
    }
}

__device__ __forceinline__ float sum8(const float* __restrict__ p, int j)
{
    float s0 = p[j] + p[512 + j];
    float s1 = p[1024 + j] + p[1536 + j];
    float s2 = p[2048 + j] + p[2560 + j];
    float s3 = p[3072 + j] + p[3584 + j];
    return (s0 + s1) + (s2 + s3);
}

__device__ __forceinline__ float mbit(const ull* __restrict__ mb, int t, int j)
{
    return ((mb[t * 8 + (j >> 6)] >> (j & 63)) & 1ull) ? 1.0f : 0.0f;
}

// 2-barrier lag pipeline, t = 0..TSTEPS+1:
//   X: all 16 waves: read ballS (written Y(t-1)), build per-class composites,
//      walk pairs -> pU1 (Wh1@s1), pU2 (Wi2@s1 + Wh2@s2), pU3 (Wi3@s2) | B1
//   Y: lower half U1(t); upper half U2(t-1), U3(t-2); write ballS        | B2
__global__ __launch_bounds__(1024)
void lsnn_main(const float* __restrict__ x,
               const float* __restrict__ Wi1,
               const float* __restrict__ bi1, const float* __restrict__ bh1,
               const float* __restrict__ bi2, const float* __restrict__ bh2,
               const float* __restrict__ bi3,
               const float* __restrict__ Wo,  const float* __restrict__ bo,
               const float* __restrict__ tau1, const float* __restrict__ tau2,
               const float* __restrict__ tau3,
               const float* __restrict__ ws,
               float* __restrict__ out)
{
    const char* wsb  = (const char*)ws;
    const char* B_H1 = wsb;
    const char* B_H2 = wsb + (2u << 20);
    const ull* mb1 = (const ull*)(ws + MBOFF_F);
    const ull* mb2 = mb1 + TSTEPS * 8;
    const ull* mb3 = mb2 + TSTEPS * 8;

    const int n     = blockIdx.x;
    const int tid   = threadIdx.x;
    const int lane  = tid & 63;
    const int w     = tid >> 6;            // wave 0..15
    const unsigned pairi = (unsigned)(w >> 1);  // byte-class 0..7
    const int u     = ((w & 1) << 6) | lane;    // 16B slice id 0..127
    const unsigned uoff = (unsigned)u << 4;
    const bool lowh = tid < 512;
    const int j     = lowh ? tid : tid - 512;
    const int w8    = (tid >> 6) & 7;

    __shared__ f4  pU1[8][128], pU2[8][128], pU3[8][128];
    __shared__ ull ballS[16];    // [0..7]=ball(s1), [8..15]=ball(s2)

    // per-half parameter/state registers
    float4 wi; float bs1, ro1, omr1, mem1, b1, s1;           // lower
    float bs2, ro2, omr2, mem2, b2, s2;                      // upper
    float bs3, ro3, omr3, mem3, b3, s3, cnt3;                // upper
    const float alpha = expf(-1.0f / 20.0f);
    const float oma = 1.0f - alpha;
    if (lowh) {
        wi  = reinterpret_cast<const float4*>(Wi1)[j];
        bs1 = bi1[j] + bh1[j];
        ro1 = expf(-1.0f / tau1[j]); omr1 = 1.0f - ro1;
        mem1 = 0.f; b1 = 0.01f; s1 = 0.f;
    } else {
        bs2 = bi2[j] + bh2[j];
        bs3 = bi3[j];
        ro2 = expf(-1.0f / tau2[j]); omr2 = 1.0f - ro2;
        ro3 = expf(-1.0f / tau3[j]); omr3 = 1.0f - ro3;
        mem2 = 0.f; b2 = 0.01f; s2 = 0.f;
        mem3 = 0.f; b3 = 0.01f; s3 = 0.f; cnt3 = 0.f;
    }

    const float* xr = x + n * FLEN;
    const unsigned shf = (pairi & 3u) * 8u;

    if (tid < 16) ballS[tid] = 0ull;
    __syncthreads();

    for (int t = 0; t <= TSTEPS + 1; ++t) {
        // ---------------- X: gather via ballot extraction ----------------
        {
            // uniform ballot words (readfirstlane anchors SALU path)
            unsigned lo1[8], hi1[8], lo2[8], hi2[8];
#pragma unroll
            for (int wd = 0; wd < 8; ++wd) {
                ull v1 = ballS[wd], v2 = ballS[8 + wd];
                lo1[wd] = __builtin_amdgcn_readfirstlane((unsigned)v1);
                hi1[wd] = __builtin_amdgcn_readfirstlane((unsigned)(v1 >> 32));
                lo2[wd] = __builtin_amdgcn_readfirstlane((unsigned)v2);
                hi2[wd] = __builtin_amdgcn_readfirstlane((unsigned)(v2 >> 32));
            }
            // composite: byte 'pairi' of each word -> byte wd of comp
            ull comp1 = 0ull, comp2 = 0ull;
#pragma unroll
            for (int wd = 0; wd < 8; ++wd) {
                unsigned by1 = ((pairi < 4u ? lo1[wd] : hi1[wd]) >> shf) & 0xFFu;
                unsigned by2 = ((pairi < 4u ? lo2[wd] : hi2[wd]) >> shf) & 0xFFu;
                comp1 |= (ull)by1 << (8 * wd);
                comp2 |= (ull)by2 << (8 * wd);
            }
            f4 aU1 = (f4)0.0f, aU2 = (f4)0.0f, aU3 = (f4)0.0f;
            walkpair(B_H1, B_H1 + (1u << 20), comp1, pairi, PAD1, uoff, aU1, aU2);
            walkpair(B_H2, B_H2 + (1u << 20), comp2, pairi, PAD2, uoff, aU2, aU3);
            pU1[pairi][u] = aU1;
            pU2[pairi][u] = aU2;
            pU3[pairi][u] = aU3;
        }
        __syncthreads();                           // B1

        // ---------------- Y: updates + ballot publish ----------------
        if (lowh) {
            ull ball = 0;
            if (t < TSTEPS) {
                float mk1 = mbit(mb1, t, j);
                int base = (t < 48) ? (4 * t) : (FLEN - 4);
                float4 xv = *reinterpret_cast<const float4*>(xr + base);
                float h1 = wi.x * xv.x + wi.y * xv.y + wi.z * xv.z + wi.w * xv.w
                         + bs1 + sum8((const float*)&pU1[0][0], j);
                b1 = ro1 * b1 + omr1 * s1;
                float Bth = 0.01f + 1.8f * b1;
                float nm = mem1 * alpha + oma * h1 - Bth * s1;
                mem1 = (mk1 == 0.0f) ? mem1 : nm;
                s1 = (mem1 - Bth > 0.0f) ? mk1 : 0.0f;
                ball = __ballot(s1 != 0.0f);
            }
            if (lane == 0) ballS[w8] = ball;
        } else {
            ull ball = 0;
            int t2 = t - 1;
            if (t2 >= 0 && t2 < TSTEPS) {
                float mk2 = mbit(mb2, t2, j);
                float h2 = bs2 + sum8((const float*)&pU2[0][0], j);
                b2 = ro2 * b2 + omr2 * s2;
                float Bth = 0.01f + 1.8f * b2;
                float nm = mem2 * alpha + oma * h2 - Bth * s2;
                mem2 = (mk2 == 0.0f) ? mem2 : nm;
                s2 = (mem2 - Bth > 0.0f) ? mk2 : 0.0f;
                ball = __ballot(s2 != 0.0f);
            }
            if (lane == 0) ballS[8 + w8] = ball;
            int t3 = t - 2;
            if (t3 >= 0 && t3 < TSTEPS) {
                float mk3 = mbit(mb3, t3, j);
                float h3 = bs3 + sum8((const float*)&pU3[0][0], j);
                b3 = ro3 * b3 + omr3 * s3;
                float Bth = 0.01f + 1.8f * b3;
                float nm = mem3 * alpha + oma * h3 - Bth * s3;
                mem3 = (mk3 == 0.0f) ? mem3 : nm;
                s3 = (mem3 - Bth > 0.0f) ? mk3 : 0.0f;
                cnt3 += s3;                        // deferred output GEMV
            }
        }
        __syncthreads();                           // B2
    }

    // ---- output: out[n,o] = (Wo[o,:]·cnt3 + T*bo[o]) / T ----
    float* c3 = (float*)&pU1[0][0];
    if (!lowh) c3[j] = cnt3;
    __syncthreads();
    int wv = tid >> 6;   // 0..15
    for (int o = wv; o < 10; o += 16) {
        float p = 0.0f;
        for (int i = lane; i < H; i += 64)
            p += Wo[o * H + i] * c3[i];
        for (int off = 32; off > 0; off >>= 1)
            p += __shfl_down(p, off);
        if (lane == 0)
            out[n * 10 + o] = (p + 196.0f * bo[o]) / 196.0f;
    }
}

extern "C" void kernel_launch(void* const* d_in, const int* in_sizes, int n_in,
                              void* d_out, int out_size, void* d_ws, size_t ws_size,
                              hipStream_t stream)
{
    const float* x    = (const float*)d_in[0];
    const float* Wi1  = (const float*)d_in[1];
    const float* bi1  = (const float*)d_in[2];
    const float* Wh1  = (const float*)d_in[3];
    const float* bh1  = (const float*)d_in[4];
    const float* Wi2  = (const float*)d_in[5];
    const float* bi2  = (const float*)d_in[6];
    const float* Wh2  = (const float*)d_in[7];
    const float* bh2  = (const float*)d_in[8];
    const float* Wi3  = (const float*)d_in[9];
    const float* bi3  = (const float*)d_in[10];
    const float* Wo   = (const float*)d_in[11];
    const float* bo   = (const float*)d_in[12];
    const float* tau1 = (const float*)d_in[13];
    const float* tau2 = (const float*)d_in[14];
    const float* tau3 = (const float*)d_in[15];
    const float* m1   = (const float*)d_in[16];
    const float* m2   = (const float*)d_in[17];
    const float* m3   = (const float*)d_in[18];

    float* ws  = (float*)d_ws;
    float* out = (float*)d_out;

    // pre-pass: transpose Wh1,Wi2,Wh2,Wi3 into 1MB slots; bitmaps + pad cols
    transpose4<<<dim3(16, 16, 4), dim3(32, 8, 1), 0, stream>>>(Wh1, Wi2, Wh2, Wi3, ws);
    maskbits<<<dim3(TSTEPS, 4, 1), 64, 0, stream>>>(m1, m2, m3, ws);

    // main persistent kernel: 1 sample per workgroup (256 WGs, 1024 thr, 16 waves)
    lsnn_main<<<NBATCH, 1024, 0, stream>>>(x, Wi1, bi1, bh1, bi2, bh2, bi3,
                                           Wo, bo, tau1, tau2, tau3, ws, out);
}